// Round 4
// baseline (283.597 us; speedup 1.0000x reference)
//
#include <hip/hip_runtime.h>
#include <stdint.h>

// Conv-TasNet Decoder:
//   frames[b,k,l] = sum_n mixture_w[b,n,k]*est_mask[b,n,k]*W[l,n]
//   out = overlap_and_add(frames, 8);  T = 8*(K-1)+16 = 128008
//
// Memory-bound: 262 MB input stream -> ~42 us floor at 6.3 TB/s.
// R3: register dbuf, 104 us — latency-bound, every pipe idle.
// R4: async global->LDS staging (global_load_lds width=16), minimal
//     2-phase pipeline (stage(c+1); compute(c); __syncthreads drain),
//     in-wave n-reduction via shfl_xor -> LDS 74 KB -> 2 blocks/CU.

#define B_ 4
#define N_ 512
#define K_ 16000
#define L_ 16
#define T_ 128008            // 8*(K_-1)+16
#define KPB 128              // k-columns per block
#define BLOCKS_PER_B 125     // K_/KPB
#define CHROWS 16            // n-rows per staged chunk
#define NCHUNKS (N_ / CHROWS)  // 32
#define FST 20               // framesS row stride (floats), 16B-aligned

typedef __attribute__((address_space(3))) uint8_t lds_u8;
typedef __attribute__((address_space(1))) const uint8_t glob_u8;

__device__ __forceinline__ void load_lds16(const float* g, float* l) {
  // 64 lanes x 16B: global src per-lane, LDS dst = uniform base + lane*16
  __builtin_amdgcn_global_load_lds((const glob_u8*)g, (lds_u8*)l, 16, 0, 0);
}

__global__ __launch_bounds__(512, 4) void decoder_kernel(
    const float* __restrict__ mw, const float* __restrict__ em,
    const float* __restrict__ W, float* __restrict__ out) {
  __shared__ float Wt[N_][L_];                 // 32 KB, Wt[n][l] = W[l][n]
  __shared__ float stage[2][2][CHROWS][KPB];   // 32 KB: [buf][m/e][row][col]
  __shared__ float framesS[KPB * FST];         // 10 KB

  const int tid = threadIdx.x;
  const int w   = tid >> 6;        // wave id 0..7
  const int kl  = tid & 63;        // lane
  const int p   = w * 16 + (kl & 15);  // k-pair index 0..127
  const int q   = kl >> 4;         // n-quarter 0..3 within chunk

  const int b  = blockIdx.x / BLOCKS_PER_B;
  const int kb = (blockIdx.x % BLOCKS_PER_B) * KPB;

  // ---- stage W transposed (vectorized f4 reads) ----
  #pragma unroll
  for (int s = 0; s < 4; ++s) {
    const int idx4 = tid + s * 512;            // [0, 2048)
    const float4 v = reinterpret_cast<const float4*>(W)[idx4];
    const int l  = idx4 >> 7;                  // (idx4*4) / 512
    const int nb = (idx4 & 127) << 2;          // (idx4*4) % 512
    Wt[nb + 0][l] = v.x; Wt[nb + 1][l] = v.y;
    Wt[nb + 2][l] = v.z; Wt[nb + 3][l] = v.w;
  }

  // ---- async stage: wave w stages rows {2w, 2w+1} of chunk for m and e ----
  const size_t bbase = (size_t)b * N_ * K_ + kb + (size_t)(kl & 31) * 4;
  const int rw = 2 * w + (kl >> 5);            // this lane's staged row 0..15

  auto stageChunk = [&](int c, int buf) {
    const int n = c * CHROWS + rw;
    const float* gm = mw + (bbase + (size_t)n * K_);
    const float* ge = em + (bbase + (size_t)n * K_);
    load_lds16(gm, &stage[buf][0][2 * w][0]);
    load_lds16(ge, &stage[buf][1][2 * w][0]);
  };

  float a0[L_], a1[L_];
  #pragma unroll
  for (int l = 0; l < L_; ++l) { a0[l] = 0.f; a1[l] = 0.f; }

  auto computeChunk = [&](int c, int buf) {
    #pragma unroll
    for (int j = 0; j < 4; ++j) {
      const int r = q * 4 + j;                 // row within chunk
      const int n = c * CHROWS + r;
      const float2 m2 = *reinterpret_cast<const float2*>(&stage[buf][0][r][2 * p]);
      const float2 e2 = *reinterpret_cast<const float2*>(&stage[buf][1][r][2 * p]);
      const float p0 = m2.x * e2.x;
      const float p1 = m2.y * e2.y;
      const float4* wv = reinterpret_cast<const float4*>(&Wt[n][0]);
      #pragma unroll
      for (int g4 = 0; g4 < 4; ++g4) {
        const float4 wq = wv[g4];
        a0[g4 * 4 + 0] += p0 * wq.x;  a1[g4 * 4 + 0] += p1 * wq.x;
        a0[g4 * 4 + 1] += p0 * wq.y;  a1[g4 * 4 + 1] += p1 * wq.y;
        a0[g4 * 4 + 2] += p0 * wq.z;  a1[g4 * 4 + 2] += p1 * wq.z;
        a0[g4 * 4 + 3] += p0 * wq.w;  a1[g4 * 4 + 3] += p1 * wq.w;
      }
    }
  };

  stageChunk(0, 0);
  __syncthreads();   // drains vmcnt+lgkmcnt (compiler) + barrier

  #pragma unroll 1
  for (int c = 0; c < NCHUNKS; c += 2) {
    if (c + 1 < NCHUNKS) stageChunk(c + 1, 1);
    computeChunk(c, 0);
    __syncthreads();
    if (c + 2 < NCHUNKS) stageChunk(c + 2, 0);
    computeChunk(c + 1, 1);
    __syncthreads();
  }

  // ---- in-wave n-reduction: lanes {q=0..3} of same p sum via shfl_xor ----
  #pragma unroll
  for (int l = 0; l < L_; ++l) {
    a0[l] += __shfl_xor(a0[l], 16);
    a0[l] += __shfl_xor(a0[l], 32);
    a1[l] += __shfl_xor(a1[l], 16);
    a1[l] += __shfl_xor(a1[l], 32);
  }
  if (q == 0) {  // 16 lanes/wave hold full frames for k-pair p
    float* f0 = &framesS[(2 * p + 0) * FST];
    float* f1 = &framesS[(2 * p + 1) * FST];
    *reinterpret_cast<float4*>(f0 + 0)  = make_float4(a0[0],  a0[1],  a0[2],  a0[3]);
    *reinterpret_cast<float4*>(f0 + 4)  = make_float4(a0[4],  a0[5],  a0[6],  a0[7]);
    *reinterpret_cast<float4*>(f0 + 8)  = make_float4(a0[8],  a0[9],  a0[10], a0[11]);
    *reinterpret_cast<float4*>(f0 + 12) = make_float4(a0[12], a0[13], a0[14], a0[15]);
    *reinterpret_cast<float4*>(f1 + 0)  = make_float4(a1[0],  a1[1],  a1[2],  a1[3]);
    *reinterpret_cast<float4*>(f1 + 4)  = make_float4(a1[4],  a1[5],  a1[6],  a1[7]);
    *reinterpret_cast<float4*>(f1 + 8)  = make_float4(a1[8],  a1[9],  a1[10], a1[11]);
    *reinterpret_cast<float4*>(f1 + 12) = make_float4(a1[12], a1[13], a1[14], a1[15]);
  }
  __syncthreads();

  // ---- overlap-add: out[8k + l] += frames[k][l], l in [0,16) ----
  if (tid < KPB) {
    const int c = tid;
    float* ob = out + (size_t)b * T_ + 8 * (size_t)(kb + c);
    const float* fc = &framesS[c * FST];
    float4 lo0 = *reinterpret_cast<const float4*>(fc + 0);  // l 0..3
    float4 lo1 = *reinterpret_cast<const float4*>(fc + 4);  // l 4..7
    if (c == 0) {
      atomicAdd(&ob[0], lo0.x); atomicAdd(&ob[1], lo0.y);
      atomicAdd(&ob[2], lo0.z); atomicAdd(&ob[3], lo0.w);
      atomicAdd(&ob[4], lo1.x); atomicAdd(&ob[5], lo1.y);
      atomicAdd(&ob[6], lo1.z); atomicAdd(&ob[7], lo1.w);
    } else {
      const float* fp = fc - FST;  // frames[c-1]
      float4 hi0 = *reinterpret_cast<const float4*>(fp + 8);
      float4 hi1 = *reinterpret_cast<const float4*>(fp + 12);
      float4 r0 = make_float4(lo0.x + hi0.x, lo0.y + hi0.y,
                              lo0.z + hi0.z, lo0.w + hi0.w);
      float4 r1 = make_float4(lo1.x + hi1.x, lo1.y + hi1.y,
                              lo1.z + hi1.z, lo1.w + hi1.w);
      *reinterpret_cast<float4*>(ob + 0) = r0;
      *reinterpret_cast<float4*>(ob + 4) = r1;
    }
    if (c == KPB - 1) {  // right boundary strip
      float4 hi0 = *reinterpret_cast<const float4*>(fc + 8);
      float4 hi1 = *reinterpret_cast<const float4*>(fc + 12);
      atomicAdd(&ob[8],  hi0.x); atomicAdd(&ob[9],  hi0.y);
      atomicAdd(&ob[10], hi0.z); atomicAdd(&ob[11], hi0.w);
      atomicAdd(&ob[12], hi1.x); atomicAdd(&ob[13], hi1.y);
      atomicAdd(&ob[14], hi1.z); atomicAdd(&ob[15], hi1.w);
    }
  }
}

extern "C" void kernel_launch(void* const* d_in, const int* in_sizes, int n_in,
                              void* d_out, int out_size, void* d_ws, size_t ws_size,
                              hipStream_t stream) {
  const float* mw = (const float*)d_in[0];
  const float* em = (const float*)d_in[1];
  const float* W  = (const float*)d_in[2];
  float* out = (float*)d_out;

  // output is re-poisoned 0xAA before every timed launch; zero it (atomics add)
  hipMemsetAsync(out, 0, (size_t)out_size * sizeof(float), stream);

  decoder_kernel<<<B_ * BLOCKS_PER_B, 512, 0, stream>>>(mw, em, W, out);
}